// Round 8
// baseline (177.827 us; speedup 1.0000x reference)
//
#include <hip/hip_runtime.h>
#include <math.h>

#define D_MODEL 4096
#define NEXP    64
#define NTOK    16384
#define KSPLIT  16
#define KS      256                // K per block (slice)
#define BMT     256                // tokens per block

typedef __attribute__((ext_vector_type(8))) short  bf16x8;
typedef __attribute__((ext_vector_type(4))) float  f32x4;

__device__ __forceinline__ unsigned short f2bf_rn(float f) {
    union { float f; unsigned u; } v; v.f = f;
    unsigned r = v.u + 0x7fffu + ((v.u >> 16) & 1u);
    return (unsigned short)(r >> 16);
}
__device__ __forceinline__ float bf2f(unsigned short h) {
    union { unsigned u; float f; } v; v.u = ((unsigned)h) << 16;
    return v.f;
}
// split two floats into packed bf16 hi-word and lo-word (RNE both)
__device__ __forceinline__ void split2(float f0, float f1, unsigned& hw, unsigned& lw) {
    unsigned short h0 = f2bf_rn(f0), h1 = f2bf_rn(f1);
    unsigned short l0 = f2bf_rn(f0 - bf2f(h0)), l1 = f2bf_rn(f1 - bf2f(h1));
    hw = (unsigned)h0 | ((unsigned)h1 << 16);
    lw = (unsigned)l0 | ((unsigned)l1 << 16);
}

// (v,i) pair merge keeping jax.lax.top_k semantics (lower index wins ties).
// Correct in butterfly reductions because partners always hold top-2 of
// DISJOINT index groups (subtree property) -> no duplicate-candidate hazard.
__device__ __forceinline__ void top2_merge(float& v1, int& i1, float& v2, int& i2,
                                           float ov1, int oi1, float ov2, int oi2) {
    if (ov1 > v1 || (ov1 == v1 && oi1 < i1)) {
        float nv2 = v1; int ni2 = i1;
        if (ov2 > nv2 || (ov2 == nv2 && oi2 < ni2)) { nv2 = ov2; ni2 = oi2; }
        v1 = ov1; i1 = oi1; v2 = nv2; i2 = ni2;
    } else {
        if (ov1 > v2 || (ov1 == v2 && oi1 < i2)) { v2 = ov1; i2 = oi1; }
    }
}

// ---------------------------------------------------------------------------
// k0: split W into bf16 hi/lo halves; zero the expert_counts tail of out.
// ---------------------------------------------------------------------------
__global__ __launch_bounds__(256)
void k0_prep(const float* __restrict__ W, unsigned short* __restrict__ ws,
             float* __restrict__ out) {
    const int gid = blockIdx.x * 256 + threadIdx.x;
    if (blockIdx.x == 0 && threadIdx.x < NEXP)
        out[(size_t)2 * NTOK * NEXP + threadIdx.x] = 0.f;
    int i = gid * 4;
    float4 v = *reinterpret_cast<const float4*>(&W[i]);
    unsigned short h[4], l[4];
    float f[4] = {v.x, v.y, v.z, v.w};
#pragma unroll
    for (int k = 0; k < 4; ++k) {
        h[k] = f2bf_rn(f[k]);
        l[k] = f2bf_rn(f[k] - bf2f(h[k]));
    }
    *reinterpret_cast<short4*>(&ws[i])                  = make_short4(h[0], h[1], h[2], h[3]);
    *reinterpret_cast<short4*>(&ws[NEXP * D_MODEL + i]) = make_short4(l[0], l[1], l[2], l[3]);
}

// ---------------------------------------------------------------------------
// k1: split-K GEMM partial (validated r7 core). Block = 256 tokens x 64
// experts x K-slice 256; W-slice (64 KB) LDS-resident loaded once; no
// in-loop barriers. Epilogue: plain streaming stores to a DISJOINT
// per-slice partial buffer (no atomics, no contention).
// ---------------------------------------------------------------------------
__global__ __launch_bounds__(512, 4)
void k1_gemm(const float* __restrict__ x, const unsigned short* __restrict__ wsplit,
             float* __restrict__ partials) {
    __shared__ uint4 whi[NEXP * 32];   // 32 KiB: [e][kchunk] 16B chunks, swizzled
    __shared__ uint4 wlo[NEXP * 32];   // 32 KiB

    const int tid = threadIdx.x;
    const int t0  = (blockIdx.x >> 4) * BMT;
    const int sl  = blockIdx.x & 15;
    const int ks0 = sl * KS;

    // ---- W-slice load (once): 4096 chunks of 16B, 8 per thread ----
#pragma unroll
    for (int i = 0; i < 4; ++i) {
        int p  = tid + i * 512;            // 0..2047
        int e  = p >> 5;                   // expert row
        int c  = p & 31;                   // k-chunk (8 bf16)
        int cs = (c & 24) | ((c & 7) ^ (e & 7));   // XOR swizzle (G4/T2)
        const unsigned short* src = wsplit + (size_t)e * D_MODEL + ks0 + c * 8;
        whi[e * 32 + cs] = *reinterpret_cast<const uint4*>(src);
        wlo[e * 32 + cs] = *reinterpret_cast<const uint4*>(src + NEXP * D_MODEL);
    }
    __syncthreads();                       // the ONLY barrier

    const int lane = tid & 63;
    const int rowl = lane & 15;
    const int grp  = lane >> 4;            // k-slot
    const int wtok = t0 + (tid >> 6) * 32;

    const float* xp0 = x + (size_t)(wtok + rowl) * D_MODEL + ks0 + grp * 8;
    const float* xp1 = xp0 + (size_t)16 * D_MODEL;

    f32x4 acc[2][4];
#pragma unroll
    for (int m = 0; m < 2; ++m)
#pragma unroll
        for (int n = 0; n < 4; ++n)
            acc[m][n] = (f32x4){0.f, 0.f, 0.f, 0.f};

#pragma unroll
    for (int kb = 0; kb < 8; ++kb) {       // 8 x K=32
        union { bf16x8 v; unsigned u[4]; } ah0, al0, ah1, al1;
        {
            f32x4 c0 = *reinterpret_cast<const f32x4*>(xp0 + kb * 32);
            f32x4 c1 = *reinterpret_cast<const f32x4*>(xp0 + kb * 32 + 4);
            split2(c0.x, c0.y, ah0.u[0], al0.u[0]);
            split2(c0.z, c0.w, ah0.u[1], al0.u[1]);
            split2(c1.x, c1.y, ah0.u[2], al0.u[2]);
            split2(c1.z, c1.w, ah0.u[3], al0.u[3]);
        }
        {
            f32x4 c0 = *reinterpret_cast<const f32x4*>(xp1 + kb * 32);
            f32x4 c1 = *reinterpret_cast<const f32x4*>(xp1 + kb * 32 + 4);
            split2(c0.x, c0.y, ah1.u[0], al1.u[0]);
            split2(c0.z, c0.w, ah1.u[1], al1.u[1]);
            split2(c1.x, c1.y, ah1.u[2], al1.u[2]);
            split2(c1.z, c1.w, ah1.u[3], al1.u[3]);
        }
        const int c  = kb * 4 + grp;
        const int cs = (c & 24) | ((c & 7) ^ (rowl & 7));   // e&7 == rowl&7
#pragma unroll
        for (int n = 0; n < 4; ++n) {
            const int idx = (n * 16 + rowl) * 32 + cs;
            bf16x8 bh = *reinterpret_cast<const bf16x8*>(&whi[idx]);
            bf16x8 bl = *reinterpret_cast<const bf16x8*>(&wlo[idx]);
            acc[0][n] = __builtin_amdgcn_mfma_f32_16x16x32_bf16(ah0.v, bh, acc[0][n], 0, 0, 0);
            acc[0][n] = __builtin_amdgcn_mfma_f32_16x16x32_bf16(ah0.v, bl, acc[0][n], 0, 0, 0);
            acc[0][n] = __builtin_amdgcn_mfma_f32_16x16x32_bf16(al0.v, bh, acc[0][n], 0, 0, 0);
            acc[1][n] = __builtin_amdgcn_mfma_f32_16x16x32_bf16(ah1.v, bh, acc[1][n], 0, 0, 0);
            acc[1][n] = __builtin_amdgcn_mfma_f32_16x16x32_bf16(ah1.v, bl, acc[1][n], 0, 0, 0);
            acc[1][n] = __builtin_amdgcn_mfma_f32_16x16x32_bf16(al1.v, bh, acc[1][n], 0, 0, 0);
        }
    }

    // streaming partial stores (disjoint per slice; D row=token=grp*4+i,
    // col=expert=rowl — convention validated r2/r4/r6/r7)
    float* part = partials + (size_t)sl * NTOK * NEXP;
#pragma unroll
    for (int m = 0; m < 2; ++m)
#pragma unroll
        for (int n = 0; n < 4; ++n)
#pragma unroll
            for (int i = 0; i < 4; ++i) {
                const int t = wtok + m * 16 + grp * 4 + i;
                const int e = n * 16 + rowl;
                part[(size_t)t * NEXP + e] = acc[m][n][i];
            }
}

// ---------------------------------------------------------------------------
// k2: wave-per-token reduction + bias + softmax + top-2 + scatter + counts.
// lane = expert. Slice-sum loads are 256 B/wave fully coalesced.
// ---------------------------------------------------------------------------
__global__ __launch_bounds__(256)
void k2_reduce_top2(const float* __restrict__ partials, const float* __restrict__ bias,
                    float* __restrict__ out) {
    __shared__ float cnt[NEXP];
    const int tid  = threadIdx.x;
    const int lane = tid & 63;            // expert e
    const int t    = blockIdx.x * 4 + (tid >> 6);

    if (tid < NEXP) cnt[tid] = 0.f;
    __syncthreads();

    const float* p = partials + (size_t)t * NEXP + lane;
    float l = 0.f;
#pragma unroll
    for (int s = 0; s < KSPLIT; ++s)
        l += p[(size_t)s * NTOK * NEXP];
    l += bias[lane];

    // 64-wide butterfly top-2 (disjoint-group invariant => correct + exact
    // lower-index tie-break)
    float v1 = l, v2 = -INFINITY;
    int   i1 = lane, i2 = 1 << 30;
#pragma unroll
    for (int mask = 1; mask < 64; mask <<= 1) {
        float ov1 = __shfl_xor(v1, mask);
        int   oi1 = __shfl_xor(i1, mask);
        float ov2 = __shfl_xor(v2, mask);
        int   oi2 = __shfl_xor(i2, mask);
        top2_merge(v1, i1, v2, i2, ov1, oi1, ov2, oi2);
    }
    // v1 == row max; softmax denominator
    float s = __expf(l - v1);
#pragma unroll
    for (int mask = 1; mask < 64; mask <<= 1) s += __shfl_xor(s, mask);

    const float invS = 1.f / s;
    const float s1 = invS;                      // exp(v1-v1)/S
    const float s2 = __expf(v2 - v1) * invS;

    const float o = (lane == i1) ? s1 : (lane == i2) ? s2 : 0.f;
    out[(size_t)t * NEXP + lane] = o;
    out[(size_t)NTOK * NEXP + (size_t)t * NEXP + lane] = o;

    if (lane == 0) {
        atomicAdd(&cnt[i1], s1);
        atomicAdd(&cnt[i2], s2);
    }
    __syncthreads();
    if (tid < NEXP)
        atomicAdd(&out[(size_t)2 * NTOK * NEXP + tid], cnt[tid]);
}

// ---------------------------------------------------------------------------
extern "C" void kernel_launch(void* const* d_in, const int* in_sizes, int n_in,
                              void* d_out, int out_size, void* d_ws, size_t ws_size,
                              hipStream_t stream) {
    const float* x = (const float*)d_in[0];
    const float* W = (const float*)d_in[1];
    const float* b = (const float*)d_in[2];
    float* out = (float*)d_out;
    unsigned short* ws = (unsigned short*)d_ws;            // 1 MiB W-split
    float* partials = (float*)(ws + 2 * NEXP * D_MODEL);   // + 64 MiB partials

    k0_prep<<<256, 256, 0, stream>>>(W, ws, out);
    k1_gemm<<<(NTOK / BMT) * KSPLIT, 512, 0, stream>>>(x, ws, partials);
    k2_reduce_top2<<<NTOK / 4, 256, 0, stream>>>(partials, b, out);
}

// Round 9
// 174.881 us; speedup vs baseline: 1.0168x; 1.0168x over previous
//
#include <hip/hip_runtime.h>
#include <math.h>

#define D_MODEL 4096
#define NEXP    64
#define NTOK    16384
#define KSPLIT  16                 // logical K-slices (atomic granularity = 2 slices)
#define KS      256                // K per LDS-resident W chunk
#define BMT     256                // tokens per block

typedef __attribute__((ext_vector_type(8))) short  bf16x8;
typedef __attribute__((ext_vector_type(4))) float  f32x4;

__device__ __forceinline__ unsigned short f2bf_rn(float f) {
    union { float f; unsigned u; } v; v.f = f;
    unsigned r = v.u + 0x7fffu + ((v.u >> 16) & 1u);
    return (unsigned short)(r >> 16);
}
__device__ __forceinline__ float bf2f(unsigned short h) {
    union { unsigned u; float f; } v; v.u = ((unsigned)h) << 16;
    return v.f;
}
// split two floats into packed bf16 hi-word and lo-word (RNE both)
__device__ __forceinline__ void split2(float f0, float f1, unsigned& hw, unsigned& lw) {
    unsigned short h0 = f2bf_rn(f0), h1 = f2bf_rn(f1);
    unsigned short l0 = f2bf_rn(f0 - bf2f(h0)), l1 = f2bf_rn(f1 - bf2f(h1));
    hw = (unsigned)h0 | ((unsigned)h1 << 16);
    lw = (unsigned)l0 | ((unsigned)l1 << 16);
}

// (v,i) pair merge keeping jax.lax.top_k semantics (lower index wins ties).
// Correct in butterfly reductions: partners hold top-2 of DISJOINT index
// groups (subtree property) -> no duplicate-candidate hazard. (validated r8)
__device__ __forceinline__ void top2_merge(float& v1, int& i1, float& v2, int& i2,
                                           float ov1, int oi1, float ov2, int oi2) {
    if (ov1 > v1 || (ov1 == v1 && oi1 < i1)) {
        float nv2 = v1; int ni2 = i1;
        if (ov2 > nv2 || (ov2 == nv2 && oi2 < ni2)) { nv2 = ov2; ni2 = oi2; }
        v1 = ov1; i1 = oi1; v2 = nv2; i2 = ni2;
    } else {
        if (ov1 > v2 || (ov1 == v2 && oi1 < i2)) { v2 = ov1; i2 = oi1; }
    }
}

// ---------------------------------------------------------------------------
// k0: split W into bf16 hi/lo halves; zero logits accumulator + counts tail.
// ---------------------------------------------------------------------------
__global__ __launch_bounds__(256)
void k0_prep(const float* __restrict__ W, unsigned short* __restrict__ ws,
             float* __restrict__ logits, float* __restrict__ out) {
    const int gid = blockIdx.x * 256 + threadIdx.x;
    if (blockIdx.x == 0 && threadIdx.x < NEXP)
        out[(size_t)2 * NTOK * NEXP + threadIdx.x] = 0.f;
    float4 z = make_float4(0.f, 0.f, 0.f, 0.f);
    float* lz = logits + (size_t)gid * 16;
#pragma unroll
    for (int k = 0; k < 4; ++k)
        *reinterpret_cast<float4*>(&lz[k * 4]) = z;
    int i = gid * 4;
    float4 v = *reinterpret_cast<const float4*>(&W[i]);
    unsigned short h[4], l[4];
    float f[4] = {v.x, v.y, v.z, v.w};
#pragma unroll
    for (int k = 0; k < 4; ++k) {
        h[k] = f2bf_rn(f[k]);
        l[k] = f2bf_rn(f[k] - bf2f(h[k]));
    }
    *reinterpret_cast<short4*>(&ws[i])                  = make_short4(h[0], h[1], h[2], h[3]);
    *reinterpret_cast<short4*>(&ws[NEXP * D_MODEL + i]) = make_short4(l[0], l[1], l[2], l[3]);
}

// ---------------------------------------------------------------------------
// k1: split-K GEMM partial (r7 core, validated). Block = 256 tokens x 64
// experts x K-slice-PAIR (512): two LDS-resident W chunks processed
// sequentially, accumulated in the same registers -> atomics halve vs r7
// (8.4M instead of 16.8M). Grid 512 = exactly 2 resident blocks/CU.
// ---------------------------------------------------------------------------
__global__ __launch_bounds__(512, 4)
void k1_gemm(const float* __restrict__ x, const unsigned short* __restrict__ wsplit,
             float* __restrict__ logits) {
    __shared__ uint4 whi[NEXP * 32];   // 32 KiB
    __shared__ uint4 wlo[NEXP * 32];   // 32 KiB

    const int tid = threadIdx.x;
    const int t0  = (blockIdx.x >> 3) * BMT;
    const int sp  = blockIdx.x & 7;    // slice pair -> K [sp*512, sp*512+512)

    const int lane = tid & 63;
    const int rowl = lane & 15;
    const int grp  = lane >> 4;        // k-slot
    const int wtok = t0 + (tid >> 6) * 32;

    f32x4 acc[2][4];
#pragma unroll
    for (int m = 0; m < 2; ++m)
#pragma unroll
        for (int n = 0; n < 4; ++n)
            acc[m][n] = (f32x4){0.f, 0.f, 0.f, 0.f};

    for (int half = 0; half < 2; ++half) {
        const int ks0 = (sp * 2 + half) * KS;
        if (half) __syncthreads();         // all waves done reading chunk A

        // ---- W-chunk load: 4096 x 16B, 8 per thread, XOR-swizzled (r7) ----
#pragma unroll
        for (int i = 0; i < 4; ++i) {
            int p  = tid + i * 512;
            int e  = p >> 5;
            int c  = p & 31;
            int cs = (c & 24) | ((c & 7) ^ (e & 7));
            const unsigned short* src = wsplit + (size_t)e * D_MODEL + ks0 + c * 8;
            whi[e * 32 + cs] = *reinterpret_cast<const uint4*>(src);
            wlo[e * 32 + cs] = *reinterpret_cast<const uint4*>(src + NEXP * D_MODEL);
        }
        __syncthreads();

        const float* xp0 = x + (size_t)(wtok + rowl) * D_MODEL + ks0 + grp * 8;
        const float* xp1 = xp0 + (size_t)16 * D_MODEL;

#pragma unroll
        for (int kb = 0; kb < 8; ++kb) {   // 8 x K=32
            union { bf16x8 v; unsigned u[4]; } ah0, al0, ah1, al1;
            {
                f32x4 c0 = *reinterpret_cast<const f32x4*>(xp0 + kb * 32);
                f32x4 c1 = *reinterpret_cast<const f32x4*>(xp0 + kb * 32 + 4);
                split2(c0.x, c0.y, ah0.u[0], al0.u[0]);
                split2(c0.z, c0.w, ah0.u[1], al0.u[1]);
                split2(c1.x, c1.y, ah0.u[2], al0.u[2]);
                split2(c1.z, c1.w, ah0.u[3], al0.u[3]);
            }
            {
                f32x4 c0 = *reinterpret_cast<const f32x4*>(xp1 + kb * 32);
                f32x4 c1 = *reinterpret_cast<const f32x4*>(xp1 + kb * 32 + 4);
                split2(c0.x, c0.y, ah1.u[0], al1.u[0]);
                split2(c0.z, c0.w, ah1.u[1], al1.u[1]);
                split2(c1.x, c1.y, ah1.u[2], al1.u[2]);
                split2(c1.z, c1.w, ah1.u[3], al1.u[3]);
            }
            const int c  = kb * 4 + grp;
            const int cs = (c & 24) | ((c & 7) ^ (rowl & 7));   // e&7 == rowl&7
#pragma unroll
            for (int n = 0; n < 4; ++n) {
                const int idx = (n * 16 + rowl) * 32 + cs;
                bf16x8 bh = *reinterpret_cast<const bf16x8*>(&whi[idx]);
                bf16x8 bl = *reinterpret_cast<const bf16x8*>(&wlo[idx]);
                acc[0][n] = __builtin_amdgcn_mfma_f32_16x16x32_bf16(ah0.v, bh, acc[0][n], 0, 0, 0);
                acc[0][n] = __builtin_amdgcn_mfma_f32_16x16x32_bf16(ah0.v, bl, acc[0][n], 0, 0, 0);
                acc[0][n] = __builtin_amdgcn_mfma_f32_16x16x32_bf16(al0.v, bh, acc[0][n], 0, 0, 0);
                acc[1][n] = __builtin_amdgcn_mfma_f32_16x16x32_bf16(ah1.v, bh, acc[1][n], 0, 0, 0);
                acc[1][n] = __builtin_amdgcn_mfma_f32_16x16x32_bf16(ah1.v, bl, acc[1][n], 0, 0, 0);
                acc[1][n] = __builtin_amdgcn_mfma_f32_16x16x32_bf16(al1.v, bh, acc[1][n], 0, 0, 0);
            }
        }
    }

    // atomic partial-logit accumulate (convention validated r2..r7)
#pragma unroll
    for (int m = 0; m < 2; ++m)
#pragma unroll
        for (int n = 0; n < 4; ++n)
#pragma unroll
            for (int i = 0; i < 4; ++i) {
                const int t = wtok + m * 16 + grp * 4 + i;
                const int e = n * 16 + rowl;
                atomicAdd(&logits[(size_t)t * NEXP + e], acc[m][n][i]);
            }
}

// ---------------------------------------------------------------------------
// k2: wave-per-token bias + softmax + top-2 + scatter + counts (r8-validated
// butterfly, reading the single logits buffer). lane = expert.
// ---------------------------------------------------------------------------
__global__ __launch_bounds__(256)
void k2_softmax_top2(const float* __restrict__ logits, const float* __restrict__ bias,
                     float* __restrict__ out) {
    __shared__ float cnt[NEXP];
    const int tid  = threadIdx.x;
    const int lane = tid & 63;            // expert e
    const int t    = blockIdx.x * 4 + (tid >> 6);

    if (tid < NEXP) cnt[tid] = 0.f;
    __syncthreads();

    float l = logits[(size_t)t * NEXP + lane] + bias[lane];

    // 64-wide butterfly top-2 (validated r8)
    float v1 = l, v2 = -INFINITY;
    int   i1 = lane, i2 = 1 << 30;
#pragma unroll
    for (int mask = 1; mask < 64; mask <<= 1) {
        float ov1 = __shfl_xor(v1, mask);
        int   oi1 = __shfl_xor(i1, mask);
        float ov2 = __shfl_xor(v2, mask);
        int   oi2 = __shfl_xor(i2, mask);
        top2_merge(v1, i1, v2, i2, ov1, oi1, ov2, oi2);
    }
    float s = __expf(l - v1);
#pragma unroll
    for (int mask = 1; mask < 64; mask <<= 1) s += __shfl_xor(s, mask);

    const float invS = 1.f / s;
    const float s1 = invS;                      // exp(v1-v1)/S
    const float s2 = __expf(v2 - v1) * invS;

    const float o = (lane == i1) ? s1 : (lane == i2) ? s2 : 0.f;
    out[(size_t)t * NEXP + lane] = o;
    out[(size_t)NTOK * NEXP + (size_t)t * NEXP + lane] = o;

    if (lane == 0) {
        atomicAdd(&cnt[i1], s1);
        atomicAdd(&cnt[i2], s2);
    }
    __syncthreads();
    if (tid < NEXP)
        atomicAdd(&out[(size_t)2 * NTOK * NEXP + tid], cnt[tid]);
}

// ---------------------------------------------------------------------------
extern "C" void kernel_launch(void* const* d_in, const int* in_sizes, int n_in,
                              void* d_out, int out_size, void* d_ws, size_t ws_size,
                              hipStream_t stream) {
    const float* x = (const float*)d_in[0];
    const float* W = (const float*)d_in[1];
    const float* b = (const float*)d_in[2];
    float* out = (float*)d_out;
    unsigned short* ws = (unsigned short*)d_ws;          // 1 MiB W-split
    float* logits = (float*)(ws + 2 * NEXP * D_MODEL);   // + 4 MiB logit accumulator

    k0_prep<<<256, 256, 0, stream>>>(W, ws, logits, out);
    k1_gemm<<<(NTOK / BMT) * (KSPLIT / 2), 512, 0, stream>>>(x, ws, logits);
    k2_softmax_top2<<<NTOK / 4, 256, 0, stream>>>(logits, b, out);
}

// Round 10
// 89.157 us; speedup vs baseline: 1.9945x; 1.9615x over previous
//
#include <hip/hip_runtime.h>
#include <math.h>

#define D_MODEL 4096
#define NEXP    64
#define NTOK    16384
#define KSPLIT  16                 // logical K-slices (atomic granularity = 2 slices)
#define KS      256                // K per LDS-resident W chunk
#define BMT     256                // tokens per block

typedef __attribute__((ext_vector_type(8))) short  bf16x8;
typedef __attribute__((ext_vector_type(4))) float  f32x4;

__device__ __forceinline__ unsigned short f2bf_rn(float f) {
    union { float f; unsigned u; } v; v.f = f;
    unsigned r = v.u + 0x7fffu + ((v.u >> 16) & 1u);
    return (unsigned short)(r >> 16);
}
__device__ __forceinline__ float bf2f(unsigned short h) {
    union { unsigned u; float f; } v; v.u = ((unsigned)h) << 16;
    return v.f;
}
// split two floats into packed bf16 hi-word and lo-word (RNE both)
__device__ __forceinline__ void split2(float f0, float f1, unsigned& hw, unsigned& lw) {
    unsigned short h0 = f2bf_rn(f0), h1 = f2bf_rn(f1);
    unsigned short l0 = f2bf_rn(f0 - bf2f(h0)), l1 = f2bf_rn(f1 - bf2f(h1));
    hw = (unsigned)h0 | ((unsigned)h1 << 16);
    lw = (unsigned)l0 | ((unsigned)l1 << 16);
}

// ---------------------------------------------------------------------------
// k0: split W into bf16 hi/lo halves; zero logits accumulator + counts tail.
// ---------------------------------------------------------------------------
__global__ __launch_bounds__(256)
void k0_prep(const float* __restrict__ W, unsigned short* __restrict__ ws,
             float* __restrict__ logits, float* __restrict__ out) {
    const int gid = blockIdx.x * 256 + threadIdx.x;
    if (blockIdx.x == 0 && threadIdx.x < NEXP)
        out[(size_t)2 * NTOK * NEXP + threadIdx.x] = 0.f;
    float4 z = make_float4(0.f, 0.f, 0.f, 0.f);
    float* lz = logits + (size_t)gid * 16;
#pragma unroll
    for (int k = 0; k < 4; ++k)
        *reinterpret_cast<float4*>(&lz[k * 4]) = z;
    int i = gid * 4;
    float4 v = *reinterpret_cast<const float4*>(&W[i]);
    unsigned short h[4], l[4];
    float f[4] = {v.x, v.y, v.z, v.w};
#pragma unroll
    for (int k = 0; k < 4; ++k) {
        h[k] = f2bf_rn(f[k]);
        l[k] = f2bf_rn(f[k] - bf2f(h[k]));
    }
    *reinterpret_cast<short4*>(&ws[i])                  = make_short4(h[0], h[1], h[2], h[3]);
    *reinterpret_cast<short4*>(&ws[NEXP * D_MODEL + i]) = make_short4(l[0], l[1], l[2], l[3]);
}

// ---------------------------------------------------------------------------
// k1: split-K GEMM partial (r9 k1, byte-identical). Block = 256 tokens x 64
// experts x K-slice-PAIR (512): two LDS-resident W chunks processed
// sequentially, accumulated in registers -> 8.4M atomics (half of r7).
// Grid 512 = 2 resident blocks/CU (LDS-capped either way).
// ---------------------------------------------------------------------------
__global__ __launch_bounds__(512, 4)
void k1_gemm(const float* __restrict__ x, const unsigned short* __restrict__ wsplit,
             float* __restrict__ logits) {
    __shared__ uint4 whi[NEXP * 32];   // 32 KiB
    __shared__ uint4 wlo[NEXP * 32];   // 32 KiB

    const int tid = threadIdx.x;
    const int t0  = (blockIdx.x >> 3) * BMT;
    const int sp  = blockIdx.x & 7;    // slice pair -> K [sp*512, sp*512+512)

    const int lane = tid & 63;
    const int rowl = lane & 15;
    const int grp  = lane >> 4;        // k-slot
    const int wtok = t0 + (tid >> 6) * 32;

    f32x4 acc[2][4];
#pragma unroll
    for (int m = 0; m < 2; ++m)
#pragma unroll
        for (int n = 0; n < 4; ++n)
            acc[m][n] = (f32x4){0.f, 0.f, 0.f, 0.f};

    for (int half = 0; half < 2; ++half) {
        const int ks0 = (sp * 2 + half) * KS;
        if (half) __syncthreads();         // all waves done reading chunk A

        // ---- W-chunk load: 4096 x 16B, 8 per thread, XOR-swizzled ----
#pragma unroll
        for (int i = 0; i < 4; ++i) {
            int p  = tid + i * 512;
            int e  = p >> 5;
            int c  = p & 31;
            int cs = (c & 24) | ((c & 7) ^ (e & 7));
            const unsigned short* src = wsplit + (size_t)e * D_MODEL + ks0 + c * 8;
            whi[e * 32 + cs] = *reinterpret_cast<const uint4*>(src);
            wlo[e * 32 + cs] = *reinterpret_cast<const uint4*>(src + NEXP * D_MODEL);
        }
        __syncthreads();

        const float* xp0 = x + (size_t)(wtok + rowl) * D_MODEL + ks0 + grp * 8;
        const float* xp1 = xp0 + (size_t)16 * D_MODEL;

#pragma unroll
        for (int kb = 0; kb < 8; ++kb) {   // 8 x K=32
            union { bf16x8 v; unsigned u[4]; } ah0, al0, ah1, al1;
            {
                f32x4 c0 = *reinterpret_cast<const f32x4*>(xp0 + kb * 32);
                f32x4 c1 = *reinterpret_cast<const f32x4*>(xp0 + kb * 32 + 4);
                split2(c0.x, c0.y, ah0.u[0], al0.u[0]);
                split2(c0.z, c0.w, ah0.u[1], al0.u[1]);
                split2(c1.x, c1.y, ah0.u[2], al0.u[2]);
                split2(c1.z, c1.w, ah0.u[3], al0.u[3]);
            }
            {
                f32x4 c0 = *reinterpret_cast<const f32x4*>(xp1 + kb * 32);
                f32x4 c1 = *reinterpret_cast<const f32x4*>(xp1 + kb * 32 + 4);
                split2(c0.x, c0.y, ah1.u[0], al1.u[0]);
                split2(c0.z, c0.w, ah1.u[1], al1.u[1]);
                split2(c1.x, c1.y, ah1.u[2], al1.u[2]);
                split2(c1.z, c1.w, ah1.u[3], al1.u[3]);
            }
            const int c  = kb * 4 + grp;
            const int cs = (c & 24) | ((c & 7) ^ (rowl & 7));   // e&7 == rowl&7
#pragma unroll
            for (int n = 0; n < 4; ++n) {
                const int idx = (n * 16 + rowl) * 32 + cs;
                bf16x8 bh = *reinterpret_cast<const bf16x8*>(&whi[idx]);
                bf16x8 bl = *reinterpret_cast<const bf16x8*>(&wlo[idx]);
                acc[0][n] = __builtin_amdgcn_mfma_f32_16x16x32_bf16(ah0.v, bh, acc[0][n], 0, 0, 0);
                acc[0][n] = __builtin_amdgcn_mfma_f32_16x16x32_bf16(ah0.v, bl, acc[0][n], 0, 0, 0);
                acc[0][n] = __builtin_amdgcn_mfma_f32_16x16x32_bf16(al0.v, bh, acc[0][n], 0, 0, 0);
                acc[1][n] = __builtin_amdgcn_mfma_f32_16x16x32_bf16(ah1.v, bh, acc[1][n], 0, 0, 0);
                acc[1][n] = __builtin_amdgcn_mfma_f32_16x16x32_bf16(ah1.v, bl, acc[1][n], 0, 0, 0);
                acc[1][n] = __builtin_amdgcn_mfma_f32_16x16x32_bf16(al1.v, bh, acc[1][n], 0, 0, 0);
            }
        }
    }

    // atomic partial-logit accumulate (convention validated r2..r9)
#pragma unroll
    for (int m = 0; m < 2; ++m)
#pragma unroll
        for (int n = 0; n < 4; ++n)
#pragma unroll
            for (int i = 0; i < 4; ++i) {
                const int t = wtok + m * 16 + grp * 4 + i;
                const int e = n * 16 + rowl;
                atomicAdd(&logits[(size_t)t * NEXP + e], acc[m][n][i]);
            }
}

// ---------------------------------------------------------------------------
// k2: per-token bias + softmax + top-2 + dense scatter + counts.
// r7's validated version: 64 blocks -> only 4096 count-atomics total
// (the r8/r9 wave-per-token k2's 262K same-address atomics were the regression).
// ---------------------------------------------------------------------------
__global__ __launch_bounds__(256)
void k2_softmax_top2(const float* __restrict__ logits, const float* __restrict__ bias,
                     float* __restrict__ out) {
    const int t = blockIdx.x * 256 + threadIdx.x;
    __shared__ float cnt[NEXP];
    __shared__ float bs[NEXP];
    if (threadIdx.x < NEXP) {
        cnt[threadIdx.x] = 0.f;
        bs[threadIdx.x]  = bias[threadIdx.x];
    }
    __syncthreads();

    float l[NEXP];
    const float* lp = logits + (size_t)t * NEXP;
#pragma unroll
    for (int g = 0; g < 16; ++g) {
        float4 v = *reinterpret_cast<const float4*>(&lp[g * 4]);
        l[4 * g + 0] = v.x + bs[4 * g + 0];
        l[4 * g + 1] = v.y + bs[4 * g + 1];
        l[4 * g + 2] = v.z + bs[4 * g + 2];
        l[4 * g + 3] = v.w + bs[4 * g + 3];
    }

    float m = l[0];
#pragma unroll
    for (int e = 1; e < NEXP; ++e) m = fmaxf(m, l[e]);

    float sum = 0.f;
#pragma unroll
    for (int e = 0; e < NEXP; ++e) sum += __expf(l[e] - m);

    float v1 = -INFINITY, v2 = -INFINITY;
    int   i1 = 0, i2 = 0;
#pragma unroll
    for (int e = 0; e < NEXP; ++e) {
        if (l[e] > v1) { v2 = v1; i2 = i1; v1 = l[e]; i1 = e; }
        else if (l[e] > v2) { v2 = l[e]; i2 = e; }
    }
    const float inv = 1.f / sum;
    const float s1 = __expf(v1 - m) * inv;
    const float s2 = __expf(v2 - m) * inv;

    float* disp = out + (size_t)t * NEXP;
    float* comb = out + (size_t)NTOK * NEXP + (size_t)t * NEXP;
#pragma unroll
    for (int g = 0; g < 16; ++g) {
        float4 o = make_float4(0.f, 0.f, 0.f, 0.f);
        if ((i1 >> 2) == g) (&o.x)[i1 & 3] = s1;
        if ((i2 >> 2) == g) (&o.x)[i2 & 3] = s2;
        *reinterpret_cast<float4*>(&disp[g * 4]) = o;
        *reinterpret_cast<float4*>(&comb[g * 4]) = o;
    }

    atomicAdd(&cnt[i1], s1);
    atomicAdd(&cnt[i2], s2);
    __syncthreads();
    if (threadIdx.x < NEXP)
        atomicAdd(&out[(size_t)2 * NTOK * NEXP + threadIdx.x], cnt[threadIdx.x]);
}

// ---------------------------------------------------------------------------
extern "C" void kernel_launch(void* const* d_in, const int* in_sizes, int n_in,
                              void* d_out, int out_size, void* d_ws, size_t ws_size,
                              hipStream_t stream) {
    const float* x = (const float*)d_in[0];
    const float* W = (const float*)d_in[1];
    const float* b = (const float*)d_in[2];
    float* out = (float*)d_out;
    unsigned short* ws = (unsigned short*)d_ws;          // 1 MiB W-split
    float* logits = (float*)(ws + 2 * NEXP * D_MODEL);   // + 4 MiB logit accumulator

    k0_prep<<<256, 256, 0, stream>>>(W, ws, logits, out);
    k1_gemm<<<(NTOK / BMT) * (KSPLIT / 2), 512, 0, stream>>>(x, ws, logits);
    k2_softmax_top2<<<NTOK / 256, 256, 0, stream>>>(logits, b, out);
}

// Round 11
// 88.100 us; speedup vs baseline: 2.0185x; 1.0120x over previous
//
#include <hip/hip_runtime.h>
#include <math.h>

#define D_MODEL 4096
#define NEXP    64
#define NTOK    16384
#define KSPLIT  16                 // logical K-slices (atomic granularity = 2 slices)
#define KS      256                // K per LDS-resident W chunk
#define BMT     256                // tokens per block

typedef __attribute__((ext_vector_type(8))) short  bf16x8;
typedef __attribute__((ext_vector_type(4))) float  f32x4;

__device__ __forceinline__ unsigned short f2bf_rn(float f) {
    union { float f; unsigned u; } v; v.f = f;
    unsigned r = v.u + 0x7fffu + ((v.u >> 16) & 1u);
    return (unsigned short)(r >> 16);
}
__device__ __forceinline__ float bf2f(unsigned short h) {
    union { unsigned u; float f; } v; v.u = ((unsigned)h) << 16;
    return v.f;
}
// split two floats into packed bf16 hi-word and lo-word (RNE both)
__device__ __forceinline__ void split2(float f0, float f1, unsigned& hw, unsigned& lw) {
    unsigned short h0 = f2bf_rn(f0), h1 = f2bf_rn(f1);
    unsigned short l0 = f2bf_rn(f0 - bf2f(h0)), l1 = f2bf_rn(f1 - bf2f(h1));
    hw = (unsigned)h0 | ((unsigned)h1 << 16);
    lw = (unsigned)l0 | ((unsigned)l1 << 16);
}

// ---------------------------------------------------------------------------
// k0: split W into bf16 hi/lo halves; zero logits accumulator + counts tail.
// ---------------------------------------------------------------------------
__global__ __launch_bounds__(256)
void k0_prep(const float* __restrict__ W, unsigned short* __restrict__ ws,
             float* __restrict__ logits, float* __restrict__ out) {
    const int gid = blockIdx.x * 256 + threadIdx.x;
    if (blockIdx.x == 0 && threadIdx.x < NEXP)
        out[(size_t)2 * NTOK * NEXP + threadIdx.x] = 0.f;
    float4 z = make_float4(0.f, 0.f, 0.f, 0.f);
    float* lz = logits + (size_t)gid * 16;
#pragma unroll
    for (int k = 0; k < 4; ++k)
        *reinterpret_cast<float4*>(&lz[k * 4]) = z;
    int i = gid * 4;
    float4 v = *reinterpret_cast<const float4*>(&W[i]);
    unsigned short h[4], l[4];
    float f[4] = {v.x, v.y, v.z, v.w};
#pragma unroll
    for (int k = 0; k < 4; ++k) {
        h[k] = f2bf_rn(f[k]);
        l[k] = f2bf_rn(f[k] - bf2f(h[k]));
    }
    *reinterpret_cast<short4*>(&ws[i])                  = make_short4(h[0], h[1], h[2], h[3]);
    *reinterpret_cast<short4*>(&ws[NEXP * D_MODEL + i]) = make_short4(l[0], l[1], l[2], l[3]);
}

// ---------------------------------------------------------------------------
// k1: split-K GEMM partial (r10 core). Block = 256 tokens x 64 experts x
// K-slice-PAIR (512); two LDS-resident W chunks sequential; 8.4M atomics.
// NEW vs r10: x loads issue 1 kb-iter AHEAD into named ping-pong registers
// (load->split->MFMA chain de-serialized; plain HIP, rule-#20-safe).
// ---------------------------------------------------------------------------
__global__ __launch_bounds__(512, 4)
void k1_gemm(const float* __restrict__ x, const unsigned short* __restrict__ wsplit,
             float* __restrict__ logits) {
    __shared__ uint4 whi[NEXP * 32];   // 32 KiB
    __shared__ uint4 wlo[NEXP * 32];   // 32 KiB

    const int tid = threadIdx.x;
    const int t0  = (blockIdx.x >> 3) * BMT;
    const int sp  = blockIdx.x & 7;    // slice pair -> K [sp*512, sp*512+512)

    const int lane = tid & 63;
    const int rowl = lane & 15;
    const int grp  = lane >> 4;        // k-slot
    const int wtok = t0 + (tid >> 6) * 32;

    f32x4 acc[2][4];
#pragma unroll
    for (int m = 0; m < 2; ++m)
#pragma unroll
        for (int n = 0; n < 4; ++n)
            acc[m][n] = (f32x4){0.f, 0.f, 0.f, 0.f};

    for (int half = 0; half < 2; ++half) {
        const int ks0 = (sp * 2 + half) * KS;
        if (half) __syncthreads();         // all waves done reading chunk A

        // ---- W-chunk load: 4096 x 16B, 8 per thread, XOR-swizzled ----
#pragma unroll
        for (int i = 0; i < 4; ++i) {
            int p  = tid + i * 512;
            int e  = p >> 5;
            int c  = p & 31;
            int cs = (c & 24) | ((c & 7) ^ (e & 7));
            const unsigned short* src = wsplit + (size_t)e * D_MODEL + ks0 + c * 8;
            whi[e * 32 + cs] = *reinterpret_cast<const uint4*>(src);
            wlo[e * 32 + cs] = *reinterpret_cast<const uint4*>(src + NEXP * D_MODEL);
        }
        __syncthreads();

        const float* xp0 = x + (size_t)(wtok + rowl) * D_MODEL + ks0 + grp * 8;
        const float* xp1 = xp0 + (size_t)16 * D_MODEL;

        // 1-ahead ping-pong prefetch (named regs, static indexing only)
        f32x4 pa0 = *reinterpret_cast<const f32x4*>(xp0);
        f32x4 pa1 = *reinterpret_cast<const f32x4*>(xp0 + 4);
        f32x4 pb0 = *reinterpret_cast<const f32x4*>(xp1);
        f32x4 pb1 = *reinterpret_cast<const f32x4*>(xp1 + 4);

#pragma unroll
        for (int kb = 0; kb < 8; ++kb) {   // 8 x K=32
            f32x4 ca0 = pa0, ca1 = pa1, cb0 = pb0, cb1 = pb1;
            if (kb < 7) {                   // issue next-iter loads EARLY
                pa0 = *reinterpret_cast<const f32x4*>(xp0 + (kb + 1) * 32);
                pa1 = *reinterpret_cast<const f32x4*>(xp0 + (kb + 1) * 32 + 4);
                pb0 = *reinterpret_cast<const f32x4*>(xp1 + (kb + 1) * 32);
                pb1 = *reinterpret_cast<const f32x4*>(xp1 + (kb + 1) * 32 + 4);
            }
            union { bf16x8 v; unsigned u[4]; } ah0, al0, ah1, al1;
            split2(ca0.x, ca0.y, ah0.u[0], al0.u[0]);
            split2(ca0.z, ca0.w, ah0.u[1], al0.u[1]);
            split2(ca1.x, ca1.y, ah0.u[2], al0.u[2]);
            split2(ca1.z, ca1.w, ah0.u[3], al0.u[3]);
            split2(cb0.x, cb0.y, ah1.u[0], al1.u[0]);
            split2(cb0.z, cb0.w, ah1.u[1], al1.u[1]);
            split2(cb1.x, cb1.y, ah1.u[2], al1.u[2]);
            split2(cb1.z, cb1.w, ah1.u[3], al1.u[3]);

            const int c  = kb * 4 + grp;
            const int cs = (c & 24) | ((c & 7) ^ (rowl & 7));   // e&7 == rowl&7
#pragma unroll
            for (int n = 0; n < 4; ++n) {
                const int idx = (n * 16 + rowl) * 32 + cs;
                bf16x8 bh = *reinterpret_cast<const bf16x8*>(&whi[idx]);
                bf16x8 bl = *reinterpret_cast<const bf16x8*>(&wlo[idx]);
                acc[0][n] = __builtin_amdgcn_mfma_f32_16x16x32_bf16(ah0.v, bh, acc[0][n], 0, 0, 0);
                acc[0][n] = __builtin_amdgcn_mfma_f32_16x16x32_bf16(ah0.v, bl, acc[0][n], 0, 0, 0);
                acc[0][n] = __builtin_amdgcn_mfma_f32_16x16x32_bf16(al0.v, bh, acc[0][n], 0, 0, 0);
                acc[1][n] = __builtin_amdgcn_mfma_f32_16x16x32_bf16(ah1.v, bh, acc[1][n], 0, 0, 0);
                acc[1][n] = __builtin_amdgcn_mfma_f32_16x16x32_bf16(ah1.v, bl, acc[1][n], 0, 0, 0);
                acc[1][n] = __builtin_amdgcn_mfma_f32_16x16x32_bf16(al1.v, bh, acc[1][n], 0, 0, 0);
            }
        }
    }

    // atomic partial-logit accumulate (convention validated r2..r10)
#pragma unroll
    for (int m = 0; m < 2; ++m)
#pragma unroll
        for (int n = 0; n < 4; ++n)
#pragma unroll
            for (int i = 0; i < 4; ++i) {
                const int t = wtok + m * 16 + grp * 4 + i;
                const int e = n * 16 + rowl;
                atomicAdd(&logits[(size_t)t * NEXP + e], acc[m][n][i]);
            }
}

// ---------------------------------------------------------------------------
// k2: per-thread-token bias + softmax + top-2 + scatter + counts (r7/r10
// validated algorithm). NEW: 128-thread blocks -> grid 128 (2x CU coverage;
// count atomics 8K total, still trivial).
// ---------------------------------------------------------------------------
__global__ __launch_bounds__(128)
void k2_softmax_top2(const float* __restrict__ logits, const float* __restrict__ bias,
                     float* __restrict__ out) {
    const int t = blockIdx.x * 128 + threadIdx.x;
    __shared__ float cnt[NEXP];
    __shared__ float bs[NEXP];
    if (threadIdx.x < NEXP) {
        cnt[threadIdx.x] = 0.f;
        bs[threadIdx.x]  = bias[threadIdx.x];
    }
    __syncthreads();

    float l[NEXP];
    const float* lp = logits + (size_t)t * NEXP;
#pragma unroll
    for (int g = 0; g < 16; ++g) {
        float4 v = *reinterpret_cast<const float4*>(&lp[g * 4]);
        l[4 * g + 0] = v.x + bs[4 * g + 0];
        l[4 * g + 1] = v.y + bs[4 * g + 1];
        l[4 * g + 2] = v.z + bs[4 * g + 2];
        l[4 * g + 3] = v.w + bs[4 * g + 3];
    }

    float m = l[0];
#pragma unroll
    for (int e = 1; e < NEXP; ++e) m = fmaxf(m, l[e]);

    float sum = 0.f;
#pragma unroll
    for (int e = 0; e < NEXP; ++e) sum += __expf(l[e] - m);

    float v1 = -INFINITY, v2 = -INFINITY;
    int   i1 = 0, i2 = 0;
#pragma unroll
    for (int e = 0; e < NEXP; ++e) {
        if (l[e] > v1) { v2 = v1; i2 = i1; v1 = l[e]; i1 = e; }
        else if (l[e] > v2) { v2 = l[e]; i2 = e; }
    }
    const float inv = 1.f / sum;
    const float s1 = __expf(v1 - m) * inv;
    const float s2 = __expf(v2 - m) * inv;

    float* disp = out + (size_t)t * NEXP;
    float* comb = out + (size_t)NTOK * NEXP + (size_t)t * NEXP;
#pragma unroll
    for (int g = 0; g < 16; ++g) {
        float4 o = make_float4(0.f, 0.f, 0.f, 0.f);
        if ((i1 >> 2) == g) (&o.x)[i1 & 3] = s1;
        if ((i2 >> 2) == g) (&o.x)[i2 & 3] = s2;
        *reinterpret_cast<float4*>(&disp[g * 4]) = o;
        *reinterpret_cast<float4*>(&comb[g * 4]) = o;
    }

    atomicAdd(&cnt[i1], s1);
    atomicAdd(&cnt[i2], s2);
    __syncthreads();
    if (threadIdx.x < NEXP)
        atomicAdd(&out[(size_t)2 * NTOK * NEXP + threadIdx.x], cnt[threadIdx.x]);
}

// ---------------------------------------------------------------------------
extern "C" void kernel_launch(void* const* d_in, const int* in_sizes, int n_in,
                              void* d_out, int out_size, void* d_ws, size_t ws_size,
                              hipStream_t stream) {
    const float* x = (const float*)d_in[0];
    const float* W = (const float*)d_in[1];
    const float* b = (const float*)d_in[2];
    float* out = (float*)d_out;
    unsigned short* ws = (unsigned short*)d_ws;          // 1 MiB W-split
    float* logits = (float*)(ws + 2 * NEXP * D_MODEL);   // + 4 MiB logit accumulator

    k0_prep<<<256, 256, 0, stream>>>(W, ws, logits, out);
    k1_gemm<<<(NTOK / BMT) * (KSPLIT / 2), 512, 0, stream>>>(x, ws, logits);
    k2_softmax_top2<<<NTOK / 128, 128, 0, stream>>>(logits, b, out);
}